// Round 5
// baseline (132.509 us; speedup 1.0000x reference)
//
#include <hip/hip_runtime.h>
#include <math.h>

#define S 256
#define V 200
#define NF 5
#define NROT 16
#define G 80
#define FG 400
#define EPSF 1e-5f
#define T2PI 6.28318530717958647692f
#define NLOG2E (-1.44269504088896340736f)
#define KP 224          // V padded to 7*32 MFMA k-steps
#define VP 228          // FtL row stride (bank-spread, 16B aligned)
#define AK 96           // K=80 padded to 96 for conv MFMA
#define CTP 17          // cT row stride (pad: breaks 16-stride bank conflicts)
#define OUT_LOSS 20480
#define OUT_SCORE 20481

typedef __attribute__((ext_vector_type(8))) short bfrag8;   // 8 bf16 (4 VGPRs)
typedef __attribute__((ext_vector_type(4))) float facc4;    // 4 f32 acc

static __device__ __forceinline__ short bft(float x) {
    return (short)(__float_as_uint(x) >> 16);   // f32 -> bf16 truncate
}
static __device__ __forceinline__ short bfr(float x) {      // round-to-nearest-even
    unsigned u = __float_as_uint(x);
    u += 0x7FFFu + ((u >> 16) & 1u);
    return (short)(u >> 16);
}

// ============ Fully fused: gaussians -> gd -> conv+max+relu -> fcc -> loss ===
// One block per s (512 thr = 8 waves). k1 phase: wave w handles r={2w,2w+1};
// rho-gauss*feat B fragments built once per wave in registers; theta-gauss A
// rebuilt per r. gd lives only in LDS (bf16, conv-A layout). Waves 0-4 run the
// 80x80 conv MFMA + max_r + relu, then fcc. Last-finished block (device-scope
// atomic counter in d_ws, zeroed by a memset node) computes score + data_loss.
__global__ __launch_bounds__(512) void k_fused(
    const float* __restrict__ feat,   // (S,V,NF)
    const float* __restrict__ rho,    // (S,V)
    const float* __restrict__ theta,  // (S,V)
    const float* __restrict__ mask,   // (S,V)
    const float* __restrict__ mu_rho, const float* __restrict__ sig_rho,
    const float* __restrict__ mu_th,  const float* __restrict__ sig_th,
    const float* __restrict__ Wc,     // (G,G)
    const float* __restrict__ bc,     // (NF,G)
    const float* __restrict__ fw,     // (FG,G)
    const float* __restrict__ fb,     // (G)
    float* __restrict__ out,          // d_out: desc | loss | score
    unsigned int* __restrict__ cnt)   // d_ws: zeroed counter
{
    const int s    = blockIdx.x;
    const int tid  = threadIdx.x;
    const int w    = __builtin_amdgcn_readfirstlane(tid >> 6);  // wave id 0..7
    const int lane = tid & 63;
    const int n    = lane & 15;
    const int quad = lane >> 4;

    __shared__ float thr[KP];            // raw theta (wrap applied per r)
    __shared__ float rhm[KP];
    __shared__ float FtL[6 * VP];        // [fh][v]: feat*mask 0..4, mask row 5
    __shared__ short A_lds[80 * AK];     // gd bf16, rows (f*16+r), k=g
    __shared__ short B_lds[80 * AK];     // WcT bf16: [col][k]
    __shared__ float cT[8 * 32 * CTP];   // per-wave C-transpose slabs
    __shared__ float desc_lds[FG];
    __shared__ float red[5 * G];
    __shared__ int   is_last;

    // ---- stage inputs ----
    if (tid < KP) {
        float th = 0.f, rh = 0.f, mk = 0.f;
        float f0 = 0.f, f1 = 0.f, f2 = 0.f, f3 = 0.f, f4 = 0.f;
        if (tid < V) {
            th = theta[s * V + tid];
            rh = rho[s * V + tid];
            mk = mask[s * V + tid];
            const float* fp = &feat[(s * V + tid) * NF];
            f0 = fp[0] * mk; f1 = fp[1] * mk; f2 = fp[2] * mk;
            f3 = fp[3] * mk; f4 = fp[4] * mk;
        }
        thr[tid] = th; rhm[tid] = rh;
        FtL[0 * VP + tid] = f0; FtL[1 * VP + tid] = f1; FtL[2 * VP + tid] = f2;
        FtL[3 * VP + tid] = f3; FtL[4 * VP + tid] = f4; FtL[5 * VP + tid] = mk;
    }
    // stage W_conv transposed -> bf16
    for (int c = tid; c < 1600; c += 512) {
        int k  = c / 20;
        int n4 = (c % 20) * 4;
        float4 v = *(const float4*)&Wc[k * G + n4];
        B_lds[(n4 + 0) * AK + k] = bfr(v.x);
        B_lds[(n4 + 1) * AK + k] = bfr(v.y);
        B_lds[(n4 + 2) * AK + k] = bfr(v.z);
        B_lds[(n4 + 3) * AK + k] = bfr(v.w);
    }
    // zero the k-pad 80..95 of both tiles
    if (tid < 160) {
        int row = tid >> 1, sg = tid & 1;
        uint4 z = {0u, 0u, 0u, 0u};
        *(uint4*)&A_lds[row * AK + 80 + sg * 8] = z;
        *(uint4*)&B_lds[row * AK + 80 + sg * 8] = z;
    }
    __syncthreads();

    // ---- per-lane gaussian constants ----
    const float mu_t = mu_th[n];
    const float stn  = sig_th[n];
    const float cth  = NLOG2E / (stn * stn + EPSF);

    const int   c0 = n;       const int ir0 = c0 / 6, fh0 = c0 % 6;
    const int   c1 = 16 + n;  const bool vl1 = (c1 < 30);
    const int   ir1 = c1 / 6;
    const int   fh1s = vl1 ? (c1 % 6) : 0;
    const float mu_r0 = mu_rho[ir0 * 16];
    const float sr0   = sig_rho[ir0 * 16];
    const float cr0   = NLOG2E / (sr0 * sr0 + EPSF);
    const float mu_r1 = mu_rho[ir1 * 16];
    const float sr1   = sig_rho[ir1 * 16];
    const float cr1   = NLOG2E / (sr1 * sr1 + EPSF);

    // ---- B fragments: rho-gaussian * feat, r-independent, built once ----
    bfrag8 B0[7], B1[7];
    #pragma unroll
    for (int kk = 0; kk < 7; ++kk) {
        const int vb = kk * 32 + quad * 8;
        const float4 p0 = *(const float4*)&rhm[vb];
        const float4 p1 = *(const float4*)&rhm[vb + 4];
        const float4 g0 = *(const float4*)&FtL[fh0 * VP + vb];
        const float4 g1 = *(const float4*)&FtL[fh0 * VP + vb + 4];
        const float4 h0 = *(const float4*)&FtL[fh1s * VP + vb];
        const float4 h1 = *(const float4*)&FtL[fh1s * VP + vb + 4];
        const float pv[8] = {p0.x, p0.y, p0.z, p0.w, p1.x, p1.y, p1.z, p1.w};
        const float gv[8] = {g0.x, g0.y, g0.z, g0.w, g1.x, g1.y, g1.z, g1.w};
        const float hv[8] = {h0.x, h0.y, h0.z, h0.w, h1.x, h1.y, h1.z, h1.w};
        bfrag8 b0, b1;
        #pragma unroll
        for (int j = 0; j < 8; ++j) {
            float dra = pv[j] - mu_r0;
            b0[j] = bft(__builtin_amdgcn_exp2f(cr0 * dra * dra) * gv[j]);
            float drb = pv[j] - mu_r1;
            float w1  = vl1 ? __builtin_amdgcn_exp2f(cr1 * drb * drb) * hv[j] : 0.f;
            b1[j] = bft(w1);
        }
        B0[kk] = b0; B1[kk] = b1;
    }

    // ---- per-r: theta-gaussian A fragment + MFMA + epilogue into A_lds ----
    float* ctw = &cT[w * 32 * CTP];
    for (int rr = 0; rr < 2; ++rr) {
        const int   r   = w * 2 + rr;
        const float rot = (float)r * (float)(6.283185307179586 / 16.0);

        facc4 acc0 = {0.f, 0.f, 0.f, 0.f};
        facc4 acc1 = {0.f, 0.f, 0.f, 0.f};
        #pragma unroll
        for (int kk = 0; kk < 7; ++kk) {
            const int vb = kk * 32 + quad * 8;
            const float4 t0 = *(const float4*)&thr[vb];
            const float4 t1 = *(const float4*)&thr[vb + 4];
            const float tv[8] = {t0.x, t0.y, t0.z, t0.w, t1.x, t1.y, t1.z, t1.w};
            bfrag8 af;
            #pragma unroll
            for (int j = 0; j < 8; ++j) {
                float u = tv[j] + rot;
                u -= (u >= T2PI) ? T2PI : 0.f;     // == jnp.mod(theta+rot, 2pi)
                float dt = u - mu_t;
                af[j] = bft(__builtin_amdgcn_exp2f(cth * dt * dt));
            }
            acc0 = __builtin_amdgcn_mfma_f32_16x16x32_bf16(af, B0[kk], acc0, 0, 0, 0);
            acc1 = __builtin_amdgcn_mfma_f32_16x16x32_bf16(af, B1[kk], acc1, 0, 0, 0);
        }

        // C/D: col=lane&15, row=quad*4+reg -> wave-private transpose slab
        #pragma unroll
        for (int i = 0; i < 4; ++i) {
            ctw[c0 * CTP + quad * 4 + i] = acc0[i];
            ctw[c1 * CTP + quad * 4 + i] = acc1[i];
        }
        // wave-private LDS: in-wave ordering via lgkmcnt, no barrier needed
        for (int i = lane; i < 400; i += 64) {
            int it  = i & 15;
            int c25 = i >> 4;                  // 0..24
            int ir  = c25 / 5, f = c25 - ir * 5;
            float num = ctw[(ir * 6 + f) * CTP + it];
            float den = ctw[(ir * 6 + 5) * CTP + it];
            float q   = num * __builtin_amdgcn_rcpf(den + EPSF);
            A_lds[(f * 16 + r) * AK + ir * 16 + it] = bfr(q);
        }
    }
    __syncthreads();

    // ---- conv MFMA: waves 0..4 (w = f), rows w*16..w*16+15, cols 80 ----
    if (w < 5) {
        facc4 a2[5];
        #pragma unroll
        for (int t = 0; t < 5; ++t) a2[t] = (facc4){0.f, 0.f, 0.f, 0.f};
        #pragma unroll
        for (int kk = 0; kk < 3; ++kk) {
            const int ko = kk * 32 + quad * 8;
            bfrag8 af2 = *(const bfrag8*)&A_lds[(w * 16 + n) * AK + ko];
            #pragma unroll
            for (int t = 0; t < 5; ++t) {
                bfrag8 bf = *(const bfrag8*)&B_lds[(t * 16 + n) * AK + ko];
                a2[t] = __builtin_amdgcn_mfma_f32_16x16x32_bf16(af2, bf, a2[t], 0, 0, 0);
            }
        }
        #pragma unroll
        for (int t = 0; t < 5; ++t) {
            float m = fmaxf(fmaxf(a2[t][0], a2[t][1]), fmaxf(a2[t][2], a2[t][3]));
            m = fmaxf(m, __shfl_xor(m, 16));
            m = fmaxf(m, __shfl_xor(m, 32));
            if (lane < 16) {
                int gout = t * 16 + n;
                desc_lds[w * G + gout] = fmaxf(m + bc[w * G + gout], 0.f);
            }
        }
    }
    __syncthreads();

    // ---- fcc: out[s,:] = desc(400) @ fw(400x80) + fb ----
    if (tid < 400) {
        const int part = tid / 80;       // 0..4
        const int gout = tid - part * 80;
        const int k0   = part * 80;
        float a3 = 0.f;
        #pragma unroll 8
        for (int i = 0; i < 80; ++i) {
            int k = k0 + i;
            a3 = fmaf(desc_lds[k], fw[k * G + gout], a3);
        }
        red[part * G + gout] = a3;
    }
    __syncthreads();
    if (tid < G) {
        out[s * G + tid] = red[tid] + red[G + tid] + red[2 * G + tid]
                         + red[3 * G + tid] + red[4 * G + tid] + fb[tid];
    }

    // ---- last-block score + loss (threadfence-reduction pattern) ----
    __threadfence();                     // flush this block's out row, dev scope
    __syncthreads();                     // all writers fenced before the atomic
    if (tid == 0) is_last = (atomicAdd(cnt, 1u) == S - 1);
    __syncthreads();
    if (!is_last) return;
    __threadfence();                     // acquire: see all blocks' out rows

    if (tid < 128) {
        const int wv   = tid >> 6;
        const int lane2 = tid & 63;
        const float* a;
        const float* b;
        if (wv == 0) { a = out + (64  + lane2) * G; b = out + lane2         * G; }
        else         { a = out + (128 + lane2) * G; b = out + (192 + lane2) * G; }

        float d = 0.f;
        #pragma unroll 8
        for (int g = 0; g < G; ++g) { float df = a[g] - b[g]; d = fmaf(df, df, d); }
        out[OUT_SCORE + tid] = d;

        float rv = (wv == 0) ? fmaxf(d - 0.0f, 0.f) : fmaxf(10.0f - d, 0.f);

        float sum = rv;
        for (int off = 32; off > 0; off >>= 1) sum += __shfl_xor(sum, off);
        float mean = sum * (1.f / 64.f);
        float dv = rv - mean;
        float sq = dv * dv;
        for (int off = 32; off > 0; off >>= 1) sq += __shfl_xor(sq, off);
        float stdv = sqrtf(sq * (1.f / 63.f));   // ddof=1

        // reuse red[] for the 2 partials
        if (lane2 == 0) red[wv] = mean + stdv;
    }
    __syncthreads();
    if (tid == 0) out[OUT_LOSS] = red[0] + red[1];
}

extern "C" void kernel_launch(void* const* d_in, const int* in_sizes, int n_in,
                              void* d_out, int out_size, void* d_ws, size_t ws_size,
                              hipStream_t stream) {
    const float* feat    = (const float*)d_in[0];
    const float* rho     = (const float*)d_in[1];
    const float* theta   = (const float*)d_in[2];
    const float* mask    = (const float*)d_in[3];
    const float* mu_rho  = (const float*)d_in[4];
    const float* sig_rho = (const float*)d_in[5];
    const float* mu_th   = (const float*)d_in[6];
    const float* sig_th  = (const float*)d_in[7];
    const float* Wc      = (const float*)d_in[8];
    const float* bc      = (const float*)d_in[9];
    const float* fw      = (const float*)d_in[10];
    const float* fb      = (const float*)d_in[11];

    float* out = (float*)d_out;
    unsigned int* cnt = (unsigned int*)d_ws;

    hipMemsetAsync(cnt, 0, sizeof(unsigned int), stream);   // counter = 0
    k_fused<<<S, 512, 0, stream>>>(feat, rho, theta, mask,
                                   mu_rho, sig_rho, mu_th, sig_th,
                                   Wc, bc, fw, fb, out, cnt);
}

// Round 6
// 94.763 us; speedup vs baseline: 1.3983x; 1.3983x over previous
//
#include <hip/hip_runtime.h>
#include <math.h>

#define S 256
#define V 200
#define NF 5
#define NROT 16
#define G 80
#define FG 400
#define EPSF 1e-5f
#define T2PI 6.28318530717958647692f
#define NLOG2E (-1.44269504088896340736f)
#define KP 224          // V padded to 7*32 MFMA k-steps
#define VP 228          // FtL row stride
#define AK 96           // K=80 padded to 96 for conv MFMA
#define BGS 232         // Bg row stride in shorts (16B-aligned rows, bank-spread)
#define OUT_LOSS 20480
#define OUT_SCORE 20481

typedef __attribute__((ext_vector_type(8))) short bfrag8;   // 8 bf16 (4 VGPRs)
typedef __attribute__((ext_vector_type(4))) float facc4;    // 4 f32 acc

static __device__ __forceinline__ short bft(float x) {
    return (short)(__float_as_uint(x) >> 16);   // f32 -> bf16 truncate
}
static __device__ __forceinline__ short bfr(float x) {      // round-to-nearest-even
    unsigned u = __float_as_uint(x);
    u += 0x7FFFu + ((u >> 16) & 1u);
    return (short)(u >> 16);
}

// ============ Fused: gaussians -> gd -> conv+max+relu -> fcc, one block/s ====
// 1024 thr = 16 waves (4 waves/SIMD). Shared bf16 B matrix (rho-gauss*feat,
// 32 cols x 224 k) built once per block in LDS; wave w = rotation r builds only
// its theta-gauss A fragments + 14 MFMA. den extracted via shuffles (C/D cols
// 5,11,17,23,29), gd written bf16 straight into the conv A-tile (no transpose
// round-trip). Waves 0-4 then run the 80x80 conv MFMA + max_r + relu; fcc last.
__global__ __launch_bounds__(1024) void k_fused(
    const float* __restrict__ feat,   // (S,V,NF)
    const float* __restrict__ rho,    // (S,V)
    const float* __restrict__ theta,  // (S,V)
    const float* __restrict__ mask,   // (S,V)
    const float* __restrict__ mu_rho, const float* __restrict__ sig_rho,
    const float* __restrict__ mu_th,  const float* __restrict__ sig_th,
    const float* __restrict__ Wc,     // (G,G)
    const float* __restrict__ bc,     // (NF,G)
    const float* __restrict__ fw,     // (FG,G)
    const float* __restrict__ fb,     // (G)
    float* __restrict__ out)          // d_out: first S*G floats
{
    const int s    = blockIdx.x;
    const int tid  = threadIdx.x;
    const int w    = __builtin_amdgcn_readfirstlane(tid >> 6);  // wave id 0..15
    const int lane = tid & 63;
    const int n    = lane & 15;
    const int quad = lane >> 4;

    __shared__ float thr[KP];            // raw theta (wrap applied per r)
    __shared__ float rhm[KP];
    __shared__ float FtL[6 * VP];        // [fh][v]: feat*mask 0..4, mask row 5
    __shared__ short Bg[32 * BGS];       // gauss B: [col](0..29 valid) x [k=v]
    __shared__ short A_lds[80 * AK];     // gd bf16, rows (f*16+r), k=g
    __shared__ short B_lds[80 * AK];     // WcT bf16: [col][k]
    __shared__ float desc_lds[FG];
    __shared__ float red[5 * G];

    // ---- stage inputs (two thread groups in parallel) ----
    if (tid < KP) {                      // theta / rho / mask
        float th = 0.f, rh = 0.f, mk = 0.f;
        if (tid < V) {
            th = theta[s * V + tid];
            rh = rho[s * V + tid];
            mk = mask[s * V + tid];
        }
        thr[tid] = th; rhm[tid] = rh; FtL[5 * VP + tid] = mk;
    }
    {                                    // feat * mask (waves 8..11)
        int t2 = tid - 512;
        if (t2 >= 0 && t2 < KP) {
            float f0 = 0.f, f1 = 0.f, f2 = 0.f, f3 = 0.f, f4 = 0.f;
            if (t2 < V) {
                float mk = mask[s * V + t2];
                const float* fp = &feat[(s * V + t2) * NF];
                f0 = fp[0] * mk; f1 = fp[1] * mk; f2 = fp[2] * mk;
                f3 = fp[3] * mk; f4 = fp[4] * mk;
            }
            FtL[0 * VP + t2] = f0; FtL[1 * VP + t2] = f1; FtL[2 * VP + t2] = f2;
            FtL[3 * VP + t2] = f3; FtL[4 * VP + t2] = f4;
        }
    }
    // stage W_conv transposed -> bf16
    for (int c = tid; c < 1600; c += 1024) {
        int k  = c / 20;
        int n4 = (c % 20) * 4;
        float4 v = *(const float4*)&Wc[k * G + n4];
        B_lds[(n4 + 0) * AK + k] = bfr(v.x);
        B_lds[(n4 + 1) * AK + k] = bfr(v.y);
        B_lds[(n4 + 2) * AK + k] = bfr(v.z);
        B_lds[(n4 + 3) * AK + k] = bfr(v.w);
    }
    // zero the k-pad 80..95 of both conv tiles
    if (tid < 160) {
        int row = tid >> 1, sg = tid & 1;
        uint4 z = {0u, 0u, 0u, 0u};
        *(uint4*)&A_lds[row * AK + 80 + sg * 8] = z;
        *(uint4*)&B_lds[row * AK + 80 + sg * 8] = z;
    }
    __syncthreads();

    // ---- cooperative Bg build: 32 cols x 224 k, 32 threads per col ----
    {
        const int  col   = tid >> 5;         // 0..31
        const int  k0    = tid & 31;
        const bool valid = col < 30;
        const int  ir    = valid ? col / 6 : 0;
        const int  fh    = valid ? col % 6 : 0;
        const float mr = mu_rho[ir * 16];
        const float sr = sig_rho[ir * 16];
        const float cr = NLOG2E / (sr * sr + EPSF);
        #pragma unroll
        for (int k = k0; k < KP; k += 32) {
            float d  = rhm[k] - mr;
            float wv = __builtin_amdgcn_exp2f(cr * d * d) * FtL[fh * VP + k];
            Bg[col * BGS + k] = valid ? bft(wv) : (short)0;
        }
    }
    __syncthreads();

    // ---- phase 1: wave w = r; theta-gauss A fragments + 14 MFMA ----
    const int   r    = w;
    const float rot  = (float)r * (float)(6.283185307179586 / 16.0);
    const float mu_t = mu_th[n];
    const float stn  = sig_th[n];
    const float cth  = NLOG2E / (stn * stn + EPSF);

    facc4 acc0 = {0.f, 0.f, 0.f, 0.f};
    facc4 acc1 = {0.f, 0.f, 0.f, 0.f};
    #pragma unroll
    for (int kk = 0; kk < 7; ++kk) {
        const int vb = kk * 32 + quad * 8;
        const float4 t0 = *(const float4*)&thr[vb];
        const float4 t1 = *(const float4*)&thr[vb + 4];
        const float tv[8] = {t0.x, t0.y, t0.z, t0.w, t1.x, t1.y, t1.z, t1.w};
        bfrag8 af;
        #pragma unroll
        for (int j = 0; j < 8; ++j) {
            float u = tv[j] + rot;
            u -= (u >= T2PI) ? T2PI : 0.f;     // == jnp.mod(theta+rot, 2pi)
            float dt = u - mu_t;
            af[j] = bft(__builtin_amdgcn_exp2f(cth * dt * dt));
        }
        bfrag8 b0 = *(const bfrag8*)&Bg[n * BGS + vb];
        bfrag8 b1 = *(const bfrag8*)&Bg[(16 + n) * BGS + vb];
        acc0 = __builtin_amdgcn_mfma_f32_16x16x32_bf16(af, b0, acc0, 0, 0, 0);
        acc1 = __builtin_amdgcn_mfma_f32_16x16x32_bf16(af, b1, acc1, 0, 0, 0);
    }

    // ---- epilogue: den via shuffles, divide, write bf16 gd into A_lds ----
    // C/D: col=lane&15 (tile0 colC=n, tile1 colC=16+n), row it=quad*4+reg.
    // den columns colC = ir*6+5: {5,11} in acc0 lanes {5,11}; {17,23,29} in
    // acc1 lanes {1,7,13}.
    {
        const int ir0  = n / 6, fh0 = n % 6;
        const int c1   = 16 + n;
        const int ir1  = c1 / 6;                 // 2..5 (5 invalid)
        const int fh1  = c1 % 6;
        const int ir1c = (ir1 > 4) ? 4 : ir1;
        const int srcA = quad * 16 + ((ir0 < 2) ? (ir0 * 6 + 5) : 5);
        const int srcB = quad * 16 + 1;          // colC=17 (den ir=2)
        const int src1 = quad * 16 + (ir1c * 6 - 11);   // {1,7,13}
        short s0[4], s1[4];
        #pragma unroll
        for (int i = 0; i < 4; ++i) {
            float dA   = __shfl(acc0[i], srcA);
            float dB   = __shfl(acc1[i], srcB);
            float den0 = (ir0 == 2) ? dB : dA;
            s0[i] = bfr(acc0[i] * __builtin_amdgcn_rcpf(den0 + EPSF));
            float d1 = __shfl(acc1[i], src1);
            s1[i] = bfr(acc1[i] * __builtin_amdgcn_rcpf(d1 + EPSF));
        }
        if (fh0 != 5) {
            uint2 pk;
            pk.x = (unsigned short)s0[0] | ((unsigned)(unsigned short)s0[1] << 16);
            pk.y = (unsigned short)s0[2] | ((unsigned)(unsigned short)s0[3] << 16);
            *(uint2*)&A_lds[(fh0 * 16 + r) * AK + ir0 * 16 + quad * 4] = pk;
        }
        if (c1 < 30 && fh1 != 5) {
            uint2 pk;
            pk.x = (unsigned short)s1[0] | ((unsigned)(unsigned short)s1[1] << 16);
            pk.y = (unsigned short)s1[2] | ((unsigned)(unsigned short)s1[3] << 16);
            *(uint2*)&A_lds[(fh1 * 16 + r) * AK + ir1 * 16 + quad * 4] = pk;
        }
    }
    __syncthreads();

    // ---- conv MFMA: waves 0..4 (w = f), rows w*16..w*16+15, cols 80 ----
    if (w < 5) {
        facc4 a2[5];
        #pragma unroll
        for (int t = 0; t < 5; ++t) a2[t] = (facc4){0.f, 0.f, 0.f, 0.f};
        #pragma unroll
        for (int kk = 0; kk < 3; ++kk) {
            const int ko = kk * 32 + quad * 8;
            bfrag8 af2 = *(const bfrag8*)&A_lds[(w * 16 + n) * AK + ko];
            #pragma unroll
            for (int t = 0; t < 5; ++t) {
                bfrag8 bf = *(const bfrag8*)&B_lds[(t * 16 + n) * AK + ko];
                a2[t] = __builtin_amdgcn_mfma_f32_16x16x32_bf16(af2, bf, a2[t], 0, 0, 0);
            }
        }
        #pragma unroll
        for (int t = 0; t < 5; ++t) {
            float m = fmaxf(fmaxf(a2[t][0], a2[t][1]), fmaxf(a2[t][2], a2[t][3]));
            m = fmaxf(m, __shfl_xor(m, 16));
            m = fmaxf(m, __shfl_xor(m, 32));
            if (lane < 16) {
                int gout = t * 16 + n;
                desc_lds[w * G + gout] = fmaxf(m + bc[w * G + gout], 0.f);
            }
        }
    }
    __syncthreads();

    // ---- fcc: out[s,:] = desc(400) @ fw(400x80) + fb ----
    if (tid < 400) {
        const int part = tid / 80;       // 0..4
        const int gout = tid - part * 80;
        const int k0   = part * 80;
        float a3 = 0.f;
        #pragma unroll 8
        for (int i = 0; i < 80; ++i) {
            int k = k0 + i;
            a3 = fmaf(desc_lds[k], fw[k * G + gout], a3);
        }
        red[part * G + gout] = a3;
    }
    __syncthreads();
    if (tid < G) {
        out[s * G + tid] = red[tid] + red[G + tid] + red[2 * G + tid]
                         + red[3 * G + tid] + red[4 * G + tid] + fb[tid];
    }
}

// ---------------- K4: score + data_loss -------------------------------------
__global__ __launch_bounds__(128) void k4_loss(
    const float* __restrict__ gdesc,  // d_out[0 .. S*G)
    float* __restrict__ out)
{
    const int tid  = threadIdx.x;
    const int wave = tid >> 6;
    const int lane = tid & 63;

    const float* a;
    const float* b;
    if (wave == 0) { a = gdesc + (64  + lane) * G; b = gdesc + lane         * G; }
    else           { a = gdesc + (128 + lane) * G; b = gdesc + (192 + lane) * G; }

    float d = 0.f;
    #pragma unroll 8
    for (int g = 0; g < G; ++g) { float df = a[g] - b[g]; d = fmaf(df, df, d); }
    out[OUT_SCORE + tid] = d;

    float rv = (wave == 0) ? fmaxf(d - 0.0f, 0.f) : fmaxf(10.0f - d, 0.f);

    float sum = rv;
    for (int off = 32; off > 0; off >>= 1) sum += __shfl_xor(sum, off);
    float mean = sum * (1.f / 64.f);
    float dv = rv - mean;
    float sq = dv * dv;
    for (int off = 32; off > 0; off >>= 1) sq += __shfl_xor(sq, off);
    float stdv = sqrtf(sq * (1.f / 63.f));   // ddof=1

    __shared__ float part[2];
    if (lane == 0) part[wave] = mean + stdv;
    __syncthreads();
    if (tid == 0) out[OUT_LOSS] = part[0] + part[1];
}

extern "C" void kernel_launch(void* const* d_in, const int* in_sizes, int n_in,
                              void* d_out, int out_size, void* d_ws, size_t ws_size,
                              hipStream_t stream) {
    const float* feat    = (const float*)d_in[0];
    const float* rho     = (const float*)d_in[1];
    const float* theta   = (const float*)d_in[2];
    const float* mask    = (const float*)d_in[3];
    const float* mu_rho  = (const float*)d_in[4];
    const float* sig_rho = (const float*)d_in[5];
    const float* mu_th   = (const float*)d_in[6];
    const float* sig_th  = (const float*)d_in[7];
    const float* Wc      = (const float*)d_in[8];
    const float* bc      = (const float*)d_in[9];
    const float* fw      = (const float*)d_in[10];
    const float* fb      = (const float*)d_in[11];

    float* out = (float*)d_out;

    k_fused<<<S, 1024, 0, stream>>>(feat, rho, theta, mask,
                                    mu_rho, sig_rho, mu_th, sig_th,
                                    Wc, bc, fw, fb, out);
    k4_loss<<<1, 128, 0, stream>>>(out, out);
}

// Round 7
// 93.774 us; speedup vs baseline: 1.4131x; 1.0106x over previous
//
#include <hip/hip_runtime.h>
#include <math.h>

#define S 256
#define V 200
#define NF 5
#define NROT 16
#define G 80
#define FG 400
#define EPSF 1e-5f
#define T2PI 6.28318530717958647692f
#define NLOG2E (-1.44269504088896340736f)
#define KP 224          // V padded to 7*32 MFMA k-steps
#define VP 228          // FtL row stride
#define AK 96           // K=80 padded to 96 for conv MFMA
#define BGS 232         // Bg row stride in shorts
#define OUT_LOSS 20480
#define OUT_SCORE 20481

typedef __attribute__((ext_vector_type(8))) short bfrag8;   // 8 bf16 (4 VGPRs)
typedef __attribute__((ext_vector_type(4))) float facc4;    // 4 f32 acc

static __device__ __forceinline__ short bft(float x) {
    return (short)(__float_as_uint(x) >> 16);   // f32 -> bf16 truncate
}
static __device__ __forceinline__ short bfr(float x) {      // round-to-nearest-even
    unsigned u = __float_as_uint(x);
    u += 0x7FFFu + ((u >> 16) & 1u);
    return (short)(u >> 16);
}

// ============ Fused: gaussians -> gd -> conv+max+relu -> fcc, one block/s ====
// 1024 thr = 16 waves (4/SIMD). W_conv is register-prefetched at entry and
// stored to LDS only after phase 1 (issue-early / wait-late), so the first
// barrier covers just 6.4 KB of per-s staging. Shared bf16 B matrix
// (rho-gauss*feat) built once in LDS; wave w = rotation r builds theta-gauss A
// fragments + 14 MFMA; den extracted via shuffles; gd written bf16 straight
// into the conv A-tile. Waves 0-4 run the 80x80 conv MFMA + max_r + relu; fcc.
__global__ __launch_bounds__(1024) void k_fused(
    const float* __restrict__ feat,   // (S,V,NF)
    const float* __restrict__ rho,    // (S,V)
    const float* __restrict__ theta,  // (S,V)
    const float* __restrict__ mask,   // (S,V)
    const float* __restrict__ mu_rho, const float* __restrict__ sig_rho,
    const float* __restrict__ mu_th,  const float* __restrict__ sig_th,
    const float* __restrict__ Wc,     // (G,G)
    const float* __restrict__ bc,     // (NF,G)
    const float* __restrict__ fw,     // (FG,G)
    const float* __restrict__ fb,     // (G)
    float* __restrict__ out)          // d_out: first S*G floats
{
    const int s    = blockIdx.x;
    const int tid  = threadIdx.x;
    const int w    = __builtin_amdgcn_readfirstlane(tid >> 6);  // wave id 0..15
    const int lane = tid & 63;
    const int n    = lane & 15;
    const int quad = lane >> 4;

    __shared__ float thr[KP];            // raw theta (wrap applied per r)
    __shared__ float rhm[KP];
    __shared__ float FtL[6 * VP];        // [fh][v]: feat*mask 0..4, mask row 5
    __shared__ short Bg[32 * BGS];       // gauss B: [col](0..29 valid) x [k=v]
    __shared__ short A_lds[80 * AK];     // gd bf16, rows (f*16+r), k=g
    __shared__ short B_lds[80 * AK];     // WcT bf16: [col][k]
    __shared__ float desc_lds[FG];
    __shared__ float red[5 * G];

    // ---- W_conv prefetch into registers (no deps; waited on after phase 1) --
    float4 wv0, wv1;
    {
        int k0 = tid / 20, m0 = (tid % 20) * 4;
        wv0 = *(const float4*)&Wc[k0 * G + m0];
        if (tid < 576) {
            int c  = tid + 1024;
            int k1 = c / 20, m1 = (c % 20) * 4;
            wv1 = *(const float4*)&Wc[k1 * G + m1];
        }
    }

    // ---- stage per-s inputs (two thread groups in parallel) ----
    if (tid < KP) {                      // theta / rho / mask
        float th = 0.f, rh = 0.f, mk = 0.f;
        if (tid < V) {
            th = theta[s * V + tid];
            rh = rho[s * V + tid];
            mk = mask[s * V + tid];
        }
        thr[tid] = th; rhm[tid] = rh; FtL[5 * VP + tid] = mk;
    }
    {                                    // feat * mask (waves 8..11)
        int t2 = tid - 512;
        if (t2 >= 0 && t2 < KP) {
            float f0 = 0.f, f1 = 0.f, f2 = 0.f, f3 = 0.f, f4 = 0.f;
            if (t2 < V) {
                float mk = mask[s * V + t2];
                const float* fp = &feat[(s * V + t2) * NF];
                f0 = fp[0] * mk; f1 = fp[1] * mk; f2 = fp[2] * mk;
                f3 = fp[3] * mk; f4 = fp[4] * mk;
            }
            FtL[0 * VP + t2] = f0; FtL[1 * VP + t2] = f1; FtL[2 * VP + t2] = f2;
            FtL[3 * VP + t2] = f3; FtL[4 * VP + t2] = f4;
        }
    }
    // zero the k-pad 80..95 of both conv tiles
    if (tid < 160) {
        int row = tid >> 1, sg = tid & 1;
        uint4 z = {0u, 0u, 0u, 0u};
        *(uint4*)&A_lds[row * AK + 80 + sg * 8] = z;
        *(uint4*)&B_lds[row * AK + 80 + sg * 8] = z;
    }
    __syncthreads();

    // ---- cooperative Bg build: 32 cols x 224 k, 32 threads per col ----
    {
        const int  col   = tid >> 5;         // 0..31
        const int  k0    = tid & 31;
        const bool valid = col < 30;
        const int  ir    = valid ? col / 6 : 0;
        const int  fh    = valid ? col % 6 : 0;
        const float mr = mu_rho[ir * 16];
        const float sr = sig_rho[ir * 16];
        const float cr = NLOG2E / (sr * sr + EPSF);
        #pragma unroll
        for (int k = k0; k < KP; k += 32) {
            float d  = rhm[k] - mr;
            float wv = __builtin_amdgcn_exp2f(cr * d * d) * FtL[fh * VP + k];
            Bg[col * BGS + k] = valid ? bft(wv) : (short)0;
        }
    }
    __syncthreads();

    // ---- phase 1: wave w = r; theta-gauss A fragments + 14 MFMA ----
    const int   r    = w;
    const float rot  = (float)r * (float)(6.283185307179586 / 16.0);
    const float mu_t = mu_th[n];
    const float stn  = sig_th[n];
    const float cth  = NLOG2E / (stn * stn + EPSF);

    facc4 acc0 = {0.f, 0.f, 0.f, 0.f};
    facc4 acc1 = {0.f, 0.f, 0.f, 0.f};
    #pragma unroll
    for (int kk = 0; kk < 7; ++kk) {
        const int vb = kk * 32 + quad * 8;
        const float4 t0 = *(const float4*)&thr[vb];
        const float4 t1 = *(const float4*)&thr[vb + 4];
        const float tv[8] = {t0.x, t0.y, t0.z, t0.w, t1.x, t1.y, t1.z, t1.w};
        bfrag8 af;
        #pragma unroll
        for (int j = 0; j < 8; ++j) {
            float u = tv[j] + rot;
            u -= (u >= T2PI) ? T2PI : 0.f;     // == jnp.mod(theta+rot, 2pi)
            float dt = u - mu_t;
            af[j] = bft(__builtin_amdgcn_exp2f(cth * dt * dt));
        }
        bfrag8 b0 = *(const bfrag8*)&Bg[n * BGS + vb];
        bfrag8 b1 = *(const bfrag8*)&Bg[(16 + n) * BGS + vb];
        acc0 = __builtin_amdgcn_mfma_f32_16x16x32_bf16(af, b0, acc0, 0, 0, 0);
        acc1 = __builtin_amdgcn_mfma_f32_16x16x32_bf16(af, b1, acc1, 0, 0, 0);
    }

    // ---- epilogue: den via shuffles, divide, write bf16 gd into A_lds ----
    // C/D: col=lane&15 (tile0 colC=n, tile1 colC=16+n), row it=quad*4+reg.
    // den columns colC = ir*6+5: {5,11} in acc0 lanes {5,11}; {17,23,29} in
    // acc1 lanes {1,7,13}.
    {
        const int ir0  = n / 6, fh0 = n % 6;
        const int c1   = 16 + n;
        const int ir1  = c1 / 6;                 // 2..5 (5 invalid)
        const int fh1  = c1 % 6;
        const int ir1c = (ir1 > 4) ? 4 : ir1;
        const int srcA = quad * 16 + ((ir0 < 2) ? (ir0 * 6 + 5) : 5);
        const int srcB = quad * 16 + 1;          // colC=17 (den ir=2)
        const int src1 = quad * 16 + (ir1c * 6 - 11);   // {1,7,13}
        short s0[4], s1[4];
        #pragma unroll
        for (int i = 0; i < 4; ++i) {
            float dA   = __shfl(acc0[i], srcA);
            float dB   = __shfl(acc1[i], srcB);
            float den0 = (ir0 == 2) ? dB : dA;
            s0[i] = bfr(acc0[i] * __builtin_amdgcn_rcpf(den0 + EPSF));
            float d1 = __shfl(acc1[i], src1);
            s1[i] = bfr(acc1[i] * __builtin_amdgcn_rcpf(d1 + EPSF));
        }
        if (fh0 != 5) {
            uint2 pk;
            pk.x = (unsigned short)s0[0] | ((unsigned)(unsigned short)s0[1] << 16);
            pk.y = (unsigned short)s0[2] | ((unsigned)(unsigned short)s0[3] << 16);
            *(uint2*)&A_lds[(fh0 * 16 + r) * AK + ir0 * 16 + quad * 4] = pk;
        }
        if (c1 < 30 && fh1 != 5) {
            uint2 pk;
            pk.x = (unsigned short)s1[0] | ((unsigned)(unsigned short)s1[1] << 16);
            pk.y = (unsigned short)s1[2] | ((unsigned)(unsigned short)s1[3] << 16);
            *(uint2*)&A_lds[(fh1 * 16 + r) * AK + ir1 * 16 + quad * 4] = pk;
        }
    }

    // ---- deferred W_conv -> B_lds (loads issued at entry are long done) ----
    {
        int k0 = tid / 20, m0 = (tid % 20) * 4;
        B_lds[(m0 + 0) * AK + k0] = bfr(wv0.x);
        B_lds[(m0 + 1) * AK + k0] = bfr(wv0.y);
        B_lds[(m0 + 2) * AK + k0] = bfr(wv0.z);
        B_lds[(m0 + 3) * AK + k0] = bfr(wv0.w);
        if (tid < 576) {
            int c  = tid + 1024;
            int k1 = c / 20, m1 = (c % 20) * 4;
            B_lds[(m1 + 0) * AK + k1] = bfr(wv1.x);
            B_lds[(m1 + 1) * AK + k1] = bfr(wv1.y);
            B_lds[(m1 + 2) * AK + k1] = bfr(wv1.z);
            B_lds[(m1 + 3) * AK + k1] = bfr(wv1.w);
        }
    }
    __syncthreads();

    // ---- conv MFMA: waves 0..4 (w = f), rows w*16..w*16+15, cols 80 ----
    if (w < 5) {
        facc4 a2[5];
        #pragma unroll
        for (int t = 0; t < 5; ++t) a2[t] = (facc4){0.f, 0.f, 0.f, 0.f};
        #pragma unroll
        for (int kk = 0; kk < 3; ++kk) {
            const int ko = kk * 32 + quad * 8;
            bfrag8 af2 = *(const bfrag8*)&A_lds[(w * 16 + n) * AK + ko];
            #pragma unroll
            for (int t = 0; t < 5; ++t) {
                bfrag8 bf = *(const bfrag8*)&B_lds[(t * 16 + n) * AK + ko];
                a2[t] = __builtin_amdgcn_mfma_f32_16x16x32_bf16(af2, bf, a2[t], 0, 0, 0);
            }
        }
        #pragma unroll
        for (int t = 0; t < 5; ++t) {
            float m = fmaxf(fmaxf(a2[t][0], a2[t][1]), fmaxf(a2[t][2], a2[t][3]));
            m = fmaxf(m, __shfl_xor(m, 16));
            m = fmaxf(m, __shfl_xor(m, 32));
            if (lane < 16) {
                int gout = t * 16 + n;
                desc_lds[w * G + gout] = fmaxf(m + bc[w * G + gout], 0.f);
            }
        }
    }
    __syncthreads();

    // ---- fcc: out[s,:] = desc(400) @ fw(400x80) + fb ----
    if (tid < 400) {
        const int part = tid / 80;       // 0..4
        const int gout = tid - part * 80;
        const int k0   = part * 80;
        float a3 = 0.f;
        #pragma unroll 8
        for (int i = 0; i < 80; ++i) {
            int k = k0 + i;
            a3 = fmaf(desc_lds[k], fw[k * G + gout], a3);
        }
        red[part * G + gout] = a3;
    }
    __syncthreads();
    if (tid < G) {
        out[s * G + tid] = red[tid] + red[G + tid] + red[2 * G + tid]
                         + red[3 * G + tid] + red[4 * G + tid] + fb[tid];
    }
}

// ---------------- K4: score + data_loss -------------------------------------
__global__ __launch_bounds__(128) void k4_loss(
    const float* __restrict__ gdesc,  // d_out[0 .. S*G)
    float* __restrict__ out)
{
    const int tid  = threadIdx.x;
    const int wave = tid >> 6;
    const int lane = tid & 63;

    const float* a;
    const float* b;
    if (wave == 0) { a = gdesc + (64  + lane) * G; b = gdesc + lane         * G; }
    else           { a = gdesc + (128 + lane) * G; b = gdesc + (192 + lane) * G; }

    float d = 0.f;
    #pragma unroll 8
    for (int g = 0; g < G; ++g) { float df = a[g] - b[g]; d = fmaf(df, df, d); }
    out[OUT_SCORE + tid] = d;

    float rv = (wave == 0) ? fmaxf(d - 0.0f, 0.f) : fmaxf(10.0f - d, 0.f);

    float sum = rv;
    for (int off = 32; off > 0; off >>= 1) sum += __shfl_xor(sum, off);
    float mean = sum * (1.f / 64.f);
    float dv = rv - mean;
    float sq = dv * dv;
    for (int off = 32; off > 0; off >>= 1) sq += __shfl_xor(sq, off);
    float stdv = sqrtf(sq * (1.f / 63.f));   // ddof=1

    __shared__ float part[2];
    if (lane == 0) part[wave] = mean + stdv;
    __syncthreads();
    if (tid == 0) out[OUT_LOSS] = part[0] + part[1];
}

extern "C" void kernel_launch(void* const* d_in, const int* in_sizes, int n_in,
                              void* d_out, int out_size, void* d_ws, size_t ws_size,
                              hipStream_t stream) {
    const float* feat    = (const float*)d_in[0];
    const float* rho     = (const float*)d_in[1];
    const float* theta   = (const float*)d_in[2];
    const float* mask    = (const float*)d_in[3];
    const float* mu_rho  = (const float*)d_in[4];
    const float* sig_rho = (const float*)d_in[5];
    const float* mu_th   = (const float*)d_in[6];
    const float* sig_th  = (const float*)d_in[7];
    const float* Wc      = (const float*)d_in[8];
    const float* bc      = (const float*)d_in[9];
    const float* fw      = (const float*)d_in[10];
    const float* fb      = (const float*)d_in[11];

    float* out = (float*)d_out;

    k_fused<<<S, 1024, 0, stream>>>(feat, rho, theta, mask,
                                    mu_rho, sig_rho, mu_th, sig_th,
                                    Wc, bc, fw, fb, out);
    k4_loss<<<1, 128, 0, stream>>>(out, out);
}